// Round 3
// baseline (9288.783 us; speedup 1.0000x reference)
//
#include <hip/hip_runtime.h>

typedef unsigned short u16;
typedef unsigned int u32;

#define B_ 4
#define T_ 2048
#define CH 64
#define TG 256      // time steps per group
#define CPG 4       // chunks per group
#define NG 8        // groups
#define KS 2        // k-splits in rhsqs

__device__ __forceinline__ float bf2f(u16 u) {
  union { u32 i; float f; } v; v.i = ((u32)u) << 16; return v.f;
}
__device__ __forceinline__ u16 f2bf(float f) {
  u32 x = __float_as_uint(f);
  return (u16)((x + 0x7FFFu + ((x >> 16) & 1u)) >> 16);
}

// ---------------------------------------------------------------------------
// Input-dtype detect: interpret first 4096 words of x as fp32. randn fp32 data
// -> ~100% in sane magnitude range; bf16-pair-packed words -> ~19%. flag=1: fp32.
// ---------------------------------------------------------------------------
__global__ __launch_bounds__(256) void detect_kernel(const u32* __restrict__ xw,
                                                     int* __restrict__ flag) {
  int tid = threadIdx.x;
  int cnt = 0;
  for (int i = tid; i < 4096; i += 256) {
    float f = __uint_as_float(xw[i]);
    float a = fabsf(f);
    if (a > 1e-8f && a < 1e8f) cnt++;   // NaN compares false -> not sane
  }
  __shared__ int sh[256];
  sh[tid] = cnt;
  __syncthreads();
  for (int s = 128; s > 0; s >>= 1) {
    if (tid < s) sh[tid] += sh[tid + s];
    __syncthreads();
  }
  if (tid == 0) *flag = (sh[0] > 3686) ? 1 : 0;  // >90% sane
}

// ---------------------------------------------------------------------------
// QKV projection for one time-group. Local row = b*TG+tt (1024 rows),
// global X row = b*2048 + tg + tt. 128x128 tile, 8x8 micro, BK=8.
// grid (8,8,3): z picks (Wq,Qg)/(Wk,Kg)/(Wv,Vg). Outputs fp32 ws.
// ---------------------------------------------------------------------------
__global__ __launch_bounds__(256) void gemm_qkv(
    const int* __restrict__ flag, const void* __restrict__ X,
    const void* __restrict__ W0v, const void* __restrict__ W1v, const void* __restrict__ W2v,
    float* __restrict__ O0, float* __restrict__ O1, float* __restrict__ O2, int tg)
{
  const int isf = *flag;
  const int z = blockIdx.z;
  const void* Wp = (z == 0) ? W0v : ((z == 1) ? W1v : W2v);
  float* O = (z == 0) ? O0 : ((z == 1) ? O1 : O2);
  const float scale = (z == 0) ? 0.03125f : 1.0f;
  const int r0 = blockIdx.x * 128;
  const int c0 = blockIdx.y * 128;
  const int tid = threadIdx.x;
  const int tx = tid & 15, ty = tid >> 4;

  __shared__ float As[8][132];
  __shared__ float Bs[8][132];

  float acc[8][8] = {};
  const int ar = tid >> 1;
  const int ak = (tid & 1) * 4;
  const int bk = tid >> 5;
  const int bn = (tid & 31) * 4;

  const int lr = r0 + ar;
  const int grow = (lr >> 8) * 2048 + tg + (lr & 255);

  const float* Xf = (const float*)X; const u16* Xh = (const u16*)X;
  const float* Wf = (const float*)Wp; const u16* Wh = (const u16*)Wp;

  for (int k0 = 0; k0 < 1024; k0 += 8) {
    float4 a4, b4;
    if (isf) {
      a4 = *reinterpret_cast<const float4*>(&Xf[grow * 1024 + k0 + ak]);
      b4 = *reinterpret_cast<const float4*>(&Wf[(k0 + bk) * 1024 + c0 + bn]);
    } else {
      ushort4 au = *reinterpret_cast<const ushort4*>(&Xh[grow * 1024 + k0 + ak]);
      ushort4 bu = *reinterpret_cast<const ushort4*>(&Wh[(k0 + bk) * 1024 + c0 + bn]);
      a4 = make_float4(bf2f(au.x), bf2f(au.y), bf2f(au.z), bf2f(au.w));
      b4 = make_float4(bf2f(bu.x), bf2f(bu.y), bf2f(bu.z), bf2f(bu.w));
    }
    __syncthreads();
    As[ak + 0][ar] = a4.x;
    As[ak + 1][ar] = a4.y;
    As[ak + 2][ar] = a4.z;
    As[ak + 3][ar] = a4.w;
    *reinterpret_cast<float4*>(&Bs[bk][bn]) = b4;
    __syncthreads();
#pragma unroll
    for (int kk = 0; kk < 8; ++kk) {
      float4 a0 = *reinterpret_cast<const float4*>(&As[kk][ty * 8]);
      float4 a1 = *reinterpret_cast<const float4*>(&As[kk][ty * 8 + 4]);
      float4 b0 = *reinterpret_cast<const float4*>(&Bs[kk][tx * 8]);
      float4 b1 = *reinterpret_cast<const float4*>(&Bs[kk][tx * 8 + 4]);
      float av[8] = {a0.x, a0.y, a0.z, a0.w, a1.x, a1.y, a1.z, a1.w};
      float bv[8] = {b0.x, b0.y, b0.z, b0.w, b1.x, b1.y, b1.z, b1.w};
#pragma unroll
      for (int i = 0; i < 8; ++i)
#pragma unroll
        for (int j = 0; j < 8; ++j) acc[i][j] += av[i] * bv[j];
    }
  }
#pragma unroll
  for (int i = 0; i < 8; ++i) {
    int row = r0 + ty * 8 + i;
#pragma unroll
    for (int j0 = 0; j0 < 8; j0 += 4) {
      float4 o = make_float4(acc[i][j0 + 0] * scale, acc[i][j0 + 1] * scale,
                             acc[i][j0 + 2] * scale, acc[i][j0 + 3] * scale);
      *reinterpret_cast<float4*>(&O[row * 1024 + c0 + tx * 8 + j0]) = o;
    }
  }
}

// ---------------------------------------------------------------------------
// Output projection for one group: out[grow] = Og[lrow] @ Wo.
// 64x64 tiles, 4x4 micro, BK=16, grid (16,16). Og fp32 ws; Wo/out per flag.
// ---------------------------------------------------------------------------
__global__ __launch_bounds__(256) void gemm_out(
    const int* __restrict__ flag, const float* __restrict__ Og,
    const void* __restrict__ Wov, void* __restrict__ outv, int tg)
{
  const int isf = *flag;
  const int r0 = blockIdx.x * 64;
  const int c0 = blockIdx.y * 64;
  const int tid = threadIdx.x;
  const int tx = tid & 15, ty = tid >> 4;
  __shared__ float As[16][68];
  __shared__ float Bs[16][68];
  float acc[4][4] = {};
  const int ar = tid & 63;
  const int ak = (tid >> 6) * 4;
  const int bk = tid >> 4;
  const int bn = (tid & 15) * 4;

  const float* Wf = (const float*)Wov; const u16* Wh = (const u16*)Wov;

  for (int k0 = 0; k0 < 1024; k0 += 16) {
    float4 a4 = *reinterpret_cast<const float4*>(&Og[(r0 + ar) * 1024 + k0 + ak]);
    float4 b4;
    if (isf) {
      b4 = *reinterpret_cast<const float4*>(&Wf[(k0 + bk) * 1024 + c0 + bn]);
    } else {
      ushort4 bu = *reinterpret_cast<const ushort4*>(&Wh[(k0 + bk) * 1024 + c0 + bn]);
      b4 = make_float4(bf2f(bu.x), bf2f(bu.y), bf2f(bu.z), bf2f(bu.w));
    }
    __syncthreads();
    As[ak + 0][ar] = a4.x;
    As[ak + 1][ar] = a4.y;
    As[ak + 2][ar] = a4.z;
    As[ak + 3][ar] = a4.w;
    *reinterpret_cast<float4*>(&Bs[bk][bn]) = b4;
    __syncthreads();
#pragma unroll
    for (int kk = 0; kk < 16; ++kk) {
      float4 av = *reinterpret_cast<const float4*>(&As[kk][ty * 4]);
      float4 bv = *reinterpret_cast<const float4*>(&Bs[kk][tx * 4]);
      float a[4] = {av.x, av.y, av.z, av.w};
      float b[4] = {bv.x, bv.y, bv.z, bv.w};
#pragma unroll
      for (int i = 0; i < 4; ++i)
#pragma unroll
        for (int j = 0; j < 4; ++j) acc[i][j] += a[i] * b[j];
    }
  }
#pragma unroll
  for (int i = 0; i < 4; ++i) {
    int lrow = r0 + ty * 4 + i;
    int grow = (lrow >> 8) * 2048 + tg + (lrow & 255);
    if (isf) {
      float4 o = make_float4(acc[i][0], acc[i][1], acc[i][2], acc[i][3]);
      *reinterpret_cast<float4*>(&((float*)outv)[grow * 1024 + c0 + tx * 4]) = o;
    } else {
      ushort4 o;
      o.x = f2bf(acc[i][0]); o.y = f2bf(acc[i][1]);
      o.z = f2bf(acc[i][2]); o.w = f2bf(acc[i][3]);
      *reinterpret_cast<ushort4*>(&((u16*)outv)[grow * 1024 + c0 + tx * 4]) = o;
    }
  }
}

// ---------------------------------------------------------------------------
// Row-normalize Kg (1024 rows of 1024, fp32)
// ---------------------------------------------------------------------------
__global__ __launch_bounds__(256) void knorm_kernel(float* __restrict__ K) {
  const int row = blockIdx.x;
  const int tid = threadIdx.x;
  float4 v4 = *reinterpret_cast<const float4*>(&K[row * 1024 + tid * 4]);
  float ss = v4.x * v4.x + v4.y * v4.y + v4.z * v4.z + v4.w * v4.w;
#pragma unroll
  for (int off = 32; off > 0; off >>= 1) ss += __shfl_down(ss, off);
  __shared__ float wsum[4];
  if ((tid & 63) == 0) wsum[tid >> 6] = ss;
  __syncthreads();
  float tot = wsum[0] + wsum[1] + wsum[2] + wsum[3];
  float inv = 1.0f / fmaxf(sqrtf(tot), 1e-12f);
  float4 o = make_float4(v4.x * inv, v4.y * inv, v4.z * inv, v4.w * inv);
  *reinterpret_cast<float4*>(&K[row * 1024 + tid * 4]) = o;
}

// ---------------------------------------------------------------------------
// A/P precompute for one group's 4 chunks (fp32 Qg/Kg).
// z=0: Ag[cc][b][t][i] = k_t.k_i (i<t else 0); z=1: Pg = q_t.k_i (i<=t else 0)
// grid (2, B, CPG)
// ---------------------------------------------------------------------------
__global__ __launch_bounds__(256) void attn_all_kernel(
    const float* __restrict__ Q, const float* __restrict__ K,
    float* __restrict__ Ag, float* __restrict__ Pg)
{
  const int z = blockIdx.x;
  const int b = blockIdx.y;
  const int cc = blockIdx.z;
  const int base = b * TG + cc * CH;
  const float* R = z ? Q : K;
  const int tid = threadIdx.x;
  const int tx = tid & 15, ty = tid >> 4;
  __shared__ float Rs[64][68];
  __shared__ float Cs[64][68];
  float acc[4][4] = {};
  for (int d0 = 0; d0 < 1024; d0 += 64) {
    __syncthreads();
#pragma unroll
    for (int i = 0; i < 4; ++i) {
      int qq = tid + i * 256;
      int t = qq >> 4, dq = (qq & 15) * 4;
      int gidx = (base + t) * 1024 + d0 + dq;
      *reinterpret_cast<float4*>(&Rs[t][dq]) = *reinterpret_cast<const float4*>(&R[gidx]);
      *reinterpret_cast<float4*>(&Cs[t][dq]) = *reinterpret_cast<const float4*>(&K[gidx]);
    }
    __syncthreads();
#pragma unroll
    for (int dd = 0; dd < 64; dd += 4) {
      float4 rv[4], cv[4];
#pragma unroll
      for (int a = 0; a < 4; ++a) rv[a] = *reinterpret_cast<const float4*>(&Rs[ty * 4 + a][dd]);
#pragma unroll
      for (int bb = 0; bb < 4; ++bb) cv[bb] = *reinterpret_cast<const float4*>(&Cs[tx * 4 + bb][dd]);
#pragma unroll
      for (int a = 0; a < 4; ++a)
#pragma unroll
        for (int bb = 0; bb < 4; ++bb)
          acc[a][bb] += rv[a].x * cv[bb].x + rv[a].y * cv[bb].y +
                        rv[a].z * cv[bb].z + rv[a].w * cv[bb].w;
    }
  }
  float* Out = z ? Pg : Ag;
#pragma unroll
  for (int a = 0; a < 4; ++a) {
    int t = ty * 4 + a;
    float4 o;
    float v0 = acc[a][0], v1 = acc[a][1], v2 = acc[a][2], v3 = acc[a][3];
    int i0 = tx * 4;
    if (z == 0) {
      o.x = (i0 + 0 < t) ? v0 : 0.0f; o.y = (i0 + 1 < t) ? v1 : 0.0f;
      o.z = (i0 + 2 < t) ? v2 : 0.0f; o.w = (i0 + 3 < t) ? v3 : 0.0f;
    } else {
      o.x = (i0 + 0 <= t) ? v0 : 0.0f; o.y = (i0 + 1 <= t) ? v1 : 0.0f;
      o.z = (i0 + 2 <= t) ? v2 : 0.0f; o.w = (i0 + 3 <= t) ? v3 : 0.0f;
    }
    *reinterpret_cast<float4*>(&Out[((cc * B_ + b) * CH + t) * 64 + i0]) = o;
  }
}

// ---------------------------------------------------------------------------
// KSp[ks][b][t][j] = sum_{d in split} K[t,d]*S[b][j][d]; same for QSp with Q.
// grid (16 jt, KS, B). Each split covers 512 d.
// ---------------------------------------------------------------------------
__global__ __launch_bounds__(256) void rhsqs_kernel(
    const float* __restrict__ Q, const float* __restrict__ K, const float* __restrict__ S,
    float* __restrict__ KSp, float* __restrict__ QSp, int cc)
{
  const int jt = blockIdx.x;
  const int ks = blockIdx.y;
  const int b = blockIdx.z;
  const int j0 = jt * 64;
  const int base = b * TG + cc * CH;
  const int tid = threadIdx.x;
  const int tx = tid & 15, ty = tid >> 4;
  __shared__ float Ks_[64][68];
  __shared__ float Qs_[64][68];
  __shared__ float Ss[64][68];
  float accK[4][4] = {};
  float accQ[4][4] = {};
  const int dbeg = ks * 512;
  for (int d0 = dbeg; d0 < dbeg + 512; d0 += 64) {
    __syncthreads();
#pragma unroll
    for (int i = 0; i < 4; ++i) {
      int qq = tid + i * 256;
      int t = qq >> 4, dq = (qq & 15) * 4;
      int gidx = (base + t) * 1024 + d0 + dq;
      *reinterpret_cast<float4*>(&Ks_[t][dq]) = *reinterpret_cast<const float4*>(&K[gidx]);
      *reinterpret_cast<float4*>(&Qs_[t][dq]) = *reinterpret_cast<const float4*>(&Q[gidx]);
      *reinterpret_cast<float4*>(&Ss[t][dq]) =
          *reinterpret_cast<const float4*>(&S[b * 1048576 + (j0 + t) * 1024 + d0 + dq]);
    }
    __syncthreads();
#pragma unroll
    for (int dd = 0; dd < 64; dd += 4) {
      float4 sv[4], kv[4], qv[4];
#pragma unroll
      for (int bb = 0; bb < 4; ++bb) sv[bb] = *reinterpret_cast<const float4*>(&Ss[tx * 4 + bb][dd]);
#pragma unroll
      for (int a = 0; a < 4; ++a) {
        kv[a] = *reinterpret_cast<const float4*>(&Ks_[ty * 4 + a][dd]);
        qv[a] = *reinterpret_cast<const float4*>(&Qs_[ty * 4 + a][dd]);
      }
#pragma unroll
      for (int a = 0; a < 4; ++a)
#pragma unroll
        for (int bb = 0; bb < 4; ++bb) {
          accK[a][bb] += kv[a].x * sv[bb].x + kv[a].y * sv[bb].y +
                         kv[a].z * sv[bb].z + kv[a].w * sv[bb].w;
          accQ[a][bb] += qv[a].x * sv[bb].x + qv[a].y * sv[bb].y +
                         qv[a].z * sv[bb].z + qv[a].w * sv[bb].w;
        }
    }
  }
#pragma unroll
  for (int a = 0; a < 4; ++a) {
    int t = ty * 4 + a;
    int oidx = ((ks * B_ + b) * CH + t) * 1024 + j0 + tx * 4;
    *reinterpret_cast<float4*>(&KSp[oidx]) =
        make_float4(accK[a][0], accK[a][1], accK[a][2], accK[a][3]);
    *reinterpret_cast<float4*>(&QSp[oidx]) =
        make_float4(accQ[a][0], accQ[a][1], accQ[a][2], accQ[a][3]);
  }
}

// ---------------------------------------------------------------------------
// Triangular solve + chunk output (fp32). One thread per DV column.
// u_t = v_t - (S0 k_t) - sum_{i<t} A[t,i] u_i ; o_t = (S0 q_t) + sum_{i<=t} P[t,i] u_i
// ---------------------------------------------------------------------------
__global__ __launch_bounds__(64) void solve_kernel(
    const float* __restrict__ Ag, const float* __restrict__ Pg,
    const float* __restrict__ KSp, const float* __restrict__ QSp,
    const float* __restrict__ V, float* __restrict__ U, float* __restrict__ Og,
    int cc)
{
  const int cg = blockIdx.x;
  const int b = blockIdx.y;
  const int col = cg * 64 + threadIdx.x;
  const int base = b * TG + cc * CH;
  __shared__ float Asm[64][64];
  __shared__ float Psm[64][64];
  const float* Ab = &Ag[((cc * B_ + b) * CH) * 64];
  const float* Pb = &Pg[((cc * B_ + b) * CH) * 64];
  for (int r = 0; r < 64; ++r) {
    Asm[r][threadIdx.x] = Ab[r * 64 + threadIdx.x];
    Psm[r][threadIdx.x] = Pb[r * 64 + threadIdx.x];
  }
  __syncthreads();

  float u[64];
#pragma unroll
  for (int t = 0; t < 64; ++t) {
    float x = V[(base + t) * 1024 + col];
#pragma unroll
    for (int ks = 0; ks < KS; ++ks) x -= KSp[((ks * B_ + b) * CH + t) * 1024 + col];
    float s0 = 0.f, s1 = 0.f, s2 = 0.f, s3 = 0.f;
    for (int i0 = 0; i0 + 4 <= t; i0 += 4) {
      float4 a4 = *reinterpret_cast<const float4*>(&Asm[t][i0]);
      s0 += a4.x * u[i0 + 0]; s1 += a4.y * u[i0 + 1];
      s2 += a4.z * u[i0 + 2]; s3 += a4.w * u[i0 + 3];
    }
    for (int i = (t >> 2) << 2; i < t; ++i) s0 += Asm[t][i] * u[i];
    u[t] = x - ((s0 + s1) + (s2 + s3));
  }
#pragma unroll
  for (int t = 0; t < 64; ++t) {
    float o = 0.f;
#pragma unroll
    for (int ks = 0; ks < KS; ++ks) o += QSp[((ks * B_ + b) * CH + t) * 1024 + col];
    float s0 = 0.f, s1 = 0.f, s2 = 0.f, s3 = 0.f;
    for (int i0 = 0; i0 + 4 <= t + 1; i0 += 4) {
      float4 p4 = *reinterpret_cast<const float4*>(&Psm[t][i0]);
      s0 += p4.x * u[i0 + 0]; s1 += p4.y * u[i0 + 1];
      s2 += p4.z * u[i0 + 2]; s3 += p4.w * u[i0 + 3];
    }
    for (int i = ((t + 1) >> 2) << 2; i <= t; ++i) s0 += Psm[t][i] * u[i];
    o += (s0 + s1) + (s2 + s3);
    U[(b * CH + t) * 1024 + col] = u[t];
    Og[(base + t) * 1024 + col] = o;
  }
}

// ---------------------------------------------------------------------------
// S[b][j][d] += sum_t U[t][j] * K[t][d]   (rank-64 update), grid (16,16,B)
// ---------------------------------------------------------------------------
__global__ __launch_bounds__(256) void supdate_kernel(
    const float* __restrict__ U, const float* __restrict__ K, float* __restrict__ S, int cc)
{
  const int d0 = blockIdx.x * 64;
  const int j0 = blockIdx.y * 64;
  const int b = blockIdx.z;
  const int base = b * TG + cc * CH;
  const int tid = threadIdx.x;
  const int tx = tid & 15, ty = tid >> 4;
  __shared__ float Us[64][68];
  __shared__ float Ks[64][68];
#pragma unroll
  for (int i = 0; i < 4; ++i) {
    int qq = tid + i * 256;
    int t = qq >> 4, xq = (qq & 15) * 4;
    *reinterpret_cast<float4*>(&Us[t][xq]) =
        *reinterpret_cast<const float4*>(&U[(b * CH + t) * 1024 + j0 + xq]);
    *reinterpret_cast<float4*>(&Ks[t][xq]) =
        *reinterpret_cast<const float4*>(&K[(base + t) * 1024 + d0 + xq]);
  }
  __syncthreads();
  float acc[4][4] = {};
#pragma unroll
  for (int t = 0; t < 64; ++t) {
    float4 u4 = *reinterpret_cast<const float4*>(&Us[t][ty * 4]);
    float4 k4 = *reinterpret_cast<const float4*>(&Ks[t][tx * 4]);
    float ua[4] = {u4.x, u4.y, u4.z, u4.w};
    float kb[4] = {k4.x, k4.y, k4.z, k4.w};
#pragma unroll
    for (int a = 0; a < 4; ++a)
#pragma unroll
      for (int bb = 0; bb < 4; ++bb) acc[a][bb] += ua[a] * kb[bb];
  }
#pragma unroll
  for (int a = 0; a < 4; ++a) {
    int idx = b * 1048576 + (j0 + ty * 4 + a) * 1024 + d0 + tx * 4;
    float4 s4 = *reinterpret_cast<float4*>(&S[idx]);
    s4.x += acc[a][0]; s4.y += acc[a][1]; s4.z += acc[a][2]; s4.w += acc[a][3];
    *reinterpret_cast<float4*>(&S[idx]) = s4;
  }
}

// ---------------------------------------------------------------------------
extern "C" void kernel_launch(void* const* d_in, const int* in_sizes, int n_in,
                              void* d_out, int out_size, void* d_ws, size_t ws_size,
                              hipStream_t stream) {
  const void* x  = d_in[0];
  const void* Wq = d_in[1];
  const void* Wk = d_in[2];
  const void* Wv = d_in[3];
  const void* Wo = d_in[4];

  char* ws = (char*)d_ws;
  size_t off = 0;
  auto alloc = [&](size_t bytes) -> void* {
    void* p = ws + off;
    off += (bytes + 255) & ~(size_t)255;
    return p;
  };
  // Total workspace: ~39.6 MB (all fp32 group-local buffers)
  float* Qg = (float*)alloc((size_t)1024 * 1024 * 4);          // 4 MB
  float* Kg = (float*)alloc((size_t)1024 * 1024 * 4);          // 4 MB
  float* Vg = (float*)alloc((size_t)1024 * 1024 * 4);          // 4 MB
  float* Og = (float*)alloc((size_t)1024 * 1024 * 4);          // 4 MB
  float* S   = (float*)alloc((size_t)B_ * 1024 * 1024 * 4);    // 16 MB
  float* Ag  = (float*)alloc((size_t)CPG * B_ * CH * 64 * 4);  // 256 KB
  float* Pg  = (float*)alloc((size_t)CPG * B_ * CH * 64 * 4);  // 256 KB
  float* KSp = (float*)alloc((size_t)KS * B_ * CH * 1024 * 4); // 2 MB
  float* QSp = (float*)alloc((size_t)KS * B_ * CH * 1024 * 4); // 2 MB
  float* U   = (float*)alloc((size_t)B_ * CH * 1024 * 4);      // 1 MB
  int* flag  = (int*)alloc(256);

  hipMemsetAsync(S, 0, (size_t)B_ * 1024 * 1024 * 4, stream);
  detect_kernel<<<1, 256, 0, stream>>>((const u32*)x, flag);

  for (int g = 0; g < NG; ++g) {
    int tg = g * TG;
    gemm_qkv<<<dim3(8, 8, 3), 256, 0, stream>>>(flag, x, Wq, Wk, Wv, Qg, Kg, Vg, tg);
    knorm_kernel<<<1024, 256, 0, stream>>>(Kg);
    attn_all_kernel<<<dim3(2, B_, CPG), 256, 0, stream>>>(Qg, Kg, Ag, Pg);
    for (int cc = 0; cc < CPG; ++cc) {
      rhsqs_kernel<<<dim3(16, KS, B_), 256, 0, stream>>>(Qg, Kg, S, KSp, QSp, cc);
      solve_kernel<<<dim3(16, B_), 64, 0, stream>>>(Ag, Pg, KSp, QSp, Vg, U, Og, cc);
      supdate_kernel<<<dim3(16, 16, B_), 256, 0, stream>>>(U, Kg, S, cc);
    }
    gemm_out<<<dim3(16, 16), 256, 0, stream>>>(flag, Og, Wo, d_out, tg);
  }
}

// Round 4
// 3778.762 us; speedup vs baseline: 2.4582x; 2.4582x over previous
//
#include <hip/hip_runtime.h>

typedef unsigned short u16;
typedef unsigned int u32;

#define B_ 4
#define T_ 2048
#define CH 64

// ---------------------------------------------------------------------------
// QKV projection, tier-generic. Local row lr in [0, B_<<lsh); global X row =
// (lr>>lsh)*T_ + tg + (lr & ((1<<lsh)-1)). 128x128 tile, 8x8 micro, BK=8.
// grid (rows/128, 8, 3): z picks (Wq,Qg)/(Wk,Kg)/(Wv,Vg).
// ---------------------------------------------------------------------------
__global__ __launch_bounds__(256) void gemm_qkv(
    const float* __restrict__ X,
    const float* __restrict__ W0, const float* __restrict__ W1, const float* __restrict__ W2,
    float* __restrict__ O0, float* __restrict__ O1, float* __restrict__ O2,
    int tg, int lsh)
{
  const int z = blockIdx.z;
  const float* W = (z == 0) ? W0 : ((z == 1) ? W1 : W2);
  float* O = (z == 0) ? O0 : ((z == 1) ? O1 : O2);
  const float scale = (z == 0) ? 0.03125f : 1.0f;
  const int r0 = blockIdx.x * 128;
  const int c0 = blockIdx.y * 128;
  const int tid = threadIdx.x;
  const int tx = tid & 15, ty = tid >> 4;

  __shared__ float As[8][132];
  __shared__ float Bs[8][132];

  float acc[8][8] = {};
  const int ar = tid >> 1;
  const int ak = (tid & 1) * 4;
  const int bk = tid >> 5;
  const int bn = (tid & 31) * 4;

  const int lr = r0 + ar;
  const int grow = ((lr >> lsh) << 11) + tg + (lr & ((1 << lsh) - 1));

  for (int k0 = 0; k0 < 1024; k0 += 8) {
    float4 a4 = *reinterpret_cast<const float4*>(&X[grow * 1024 + k0 + ak]);
    float4 b4 = *reinterpret_cast<const float4*>(&W[(k0 + bk) * 1024 + c0 + bn]);
    __syncthreads();
    As[ak + 0][ar] = a4.x;
    As[ak + 1][ar] = a4.y;
    As[ak + 2][ar] = a4.z;
    As[ak + 3][ar] = a4.w;
    *reinterpret_cast<float4*>(&Bs[bk][bn]) = b4;
    __syncthreads();
#pragma unroll
    for (int kk = 0; kk < 8; ++kk) {
      float4 a0 = *reinterpret_cast<const float4*>(&As[kk][ty * 8]);
      float4 a1 = *reinterpret_cast<const float4*>(&As[kk][ty * 8 + 4]);
      float4 b0 = *reinterpret_cast<const float4*>(&Bs[kk][tx * 8]);
      float4 b1 = *reinterpret_cast<const float4*>(&Bs[kk][tx * 8 + 4]);
      float av[8] = {a0.x, a0.y, a0.z, a0.w, a1.x, a1.y, a1.z, a1.w};
      float bv[8] = {b0.x, b0.y, b0.z, b0.w, b1.x, b1.y, b1.z, b1.w};
#pragma unroll
      for (int i = 0; i < 8; ++i)
#pragma unroll
        for (int j = 0; j < 8; ++j) acc[i][j] += av[i] * bv[j];
    }
  }
#pragma unroll
  for (int i = 0; i < 8; ++i) {
    int row = r0 + ty * 8 + i;
#pragma unroll
    for (int j0 = 0; j0 < 8; j0 += 4) {
      float4 o = make_float4(acc[i][j0 + 0] * scale, acc[i][j0 + 1] * scale,
                             acc[i][j0 + 2] * scale, acc[i][j0 + 3] * scale);
      *reinterpret_cast<float4*>(&O[row * 1024 + c0 + tx * 8 + j0]) = o;
    }
  }
}

// ---------------------------------------------------------------------------
// Output projection: out[grow] = Og[lr] @ Wo. 64x64 tiles, 4x4 micro, BK=16.
// grid (rows/64, 16).
// ---------------------------------------------------------------------------
__global__ __launch_bounds__(256) void gemm_out(
    const float* __restrict__ Og, const float* __restrict__ Wo,
    float* __restrict__ out, int tg, int lsh)
{
  const int r0 = blockIdx.x * 64;
  const int c0 = blockIdx.y * 64;
  const int tid = threadIdx.x;
  const int tx = tid & 15, ty = tid >> 4;
  __shared__ float As[16][68];
  __shared__ float Bs[16][68];
  float acc[4][4] = {};
  const int ar = tid & 63;
  const int ak = (tid >> 6) * 4;
  const int bk = tid >> 4;
  const int bn = (tid & 15) * 4;

  for (int k0 = 0; k0 < 1024; k0 += 16) {
    float4 a4 = *reinterpret_cast<const float4*>(&Og[(r0 + ar) * 1024 + k0 + ak]);
    float4 b4 = *reinterpret_cast<const float4*>(&Wo[(k0 + bk) * 1024 + c0 + bn]);
    __syncthreads();
    As[ak + 0][ar] = a4.x;
    As[ak + 1][ar] = a4.y;
    As[ak + 2][ar] = a4.z;
    As[ak + 3][ar] = a4.w;
    *reinterpret_cast<float4*>(&Bs[bk][bn]) = b4;
    __syncthreads();
#pragma unroll
    for (int kk = 0; kk < 16; ++kk) {
      float4 av = *reinterpret_cast<const float4*>(&As[kk][ty * 4]);
      float4 bv = *reinterpret_cast<const float4*>(&Bs[kk][tx * 4]);
      float a[4] = {av.x, av.y, av.z, av.w};
      float b[4] = {bv.x, bv.y, bv.z, bv.w};
#pragma unroll
      for (int i = 0; i < 4; ++i)
#pragma unroll
        for (int j = 0; j < 4; ++j) acc[i][j] += a[i] * b[j];
    }
  }
#pragma unroll
  for (int i = 0; i < 4; ++i) {
    int lr = r0 + ty * 4 + i;
    int grow = ((lr >> lsh) << 11) + tg + (lr & ((1 << lsh) - 1));
    float4 o = make_float4(acc[i][0], acc[i][1], acc[i][2], acc[i][3]);
    *reinterpret_cast<float4*>(&out[grow * 1024 + c0 + tx * 4]) = o;
  }
}

// ---------------------------------------------------------------------------
// Row-normalize Kg (rows x 1024, fp32)
// ---------------------------------------------------------------------------
__global__ __launch_bounds__(256) void knorm_kernel(float* __restrict__ K) {
  const int row = blockIdx.x;
  const int tid = threadIdx.x;
  float4 v4 = *reinterpret_cast<const float4*>(&K[row * 1024 + tid * 4]);
  float ss = v4.x * v4.x + v4.y * v4.y + v4.z * v4.z + v4.w * v4.w;
#pragma unroll
  for (int off = 32; off > 0; off >>= 1) ss += __shfl_down(ss, off);
  __shared__ float wsum[4];
  if ((tid & 63) == 0) wsum[tid >> 6] = ss;
  __syncthreads();
  float tot = wsum[0] + wsum[1] + wsum[2] + wsum[3];
  float inv = 1.0f / fmaxf(sqrtf(tot), 1e-12f);
  float4 o = make_float4(v4.x * inv, v4.y * inv, v4.z * inv, v4.w * inv);
  *reinterpret_cast<float4*>(&K[row * 1024 + tid * 4]) = o;
}

// ---------------------------------------------------------------------------
// A/P precompute for one buffer's cpg chunks.
// z=0: Ag[cc][b][t][i] = k_t.k_i (i<t else 0); z=1: Pg = q_t.k_i (i<=t else 0)
// grid (2, B_, cpg). tgs = rows per batch in buffer.
// ---------------------------------------------------------------------------
__global__ __launch_bounds__(256) void attn_all_kernel(
    const float* __restrict__ Q, const float* __restrict__ K,
    float* __restrict__ Ag, float* __restrict__ Pg, int tgs)
{
  const int z = blockIdx.x;
  const int b = blockIdx.y;
  const int cc = blockIdx.z;
  const int base = b * tgs + cc * CH;
  const float* R = z ? Q : K;
  const int tid = threadIdx.x;
  const int tx = tid & 15, ty = tid >> 4;
  __shared__ float Rs[64][68];
  __shared__ float Cs[64][68];
  float acc[4][4] = {};
  for (int d0 = 0; d0 < 1024; d0 += 64) {
    __syncthreads();
#pragma unroll
    for (int i = 0; i < 4; ++i) {
      int qq = tid + i * 256;
      int t = qq >> 4, dq = (qq & 15) * 4;
      int gidx = (base + t) * 1024 + d0 + dq;
      *reinterpret_cast<float4*>(&Rs[t][dq]) = *reinterpret_cast<const float4*>(&R[gidx]);
      *reinterpret_cast<float4*>(&Cs[t][dq]) = *reinterpret_cast<const float4*>(&K[gidx]);
    }
    __syncthreads();
#pragma unroll
    for (int dd = 0; dd < 64; dd += 4) {
      float4 rv[4], cv[4];
#pragma unroll
      for (int a = 0; a < 4; ++a) rv[a] = *reinterpret_cast<const float4*>(&Rs[ty * 4 + a][dd]);
#pragma unroll
      for (int bb = 0; bb < 4; ++bb) cv[bb] = *reinterpret_cast<const float4*>(&Cs[tx * 4 + bb][dd]);
#pragma unroll
      for (int a = 0; a < 4; ++a)
#pragma unroll
        for (int bb = 0; bb < 4; ++bb)
          acc[a][bb] += rv[a].x * cv[bb].x + rv[a].y * cv[bb].y +
                        rv[a].z * cv[bb].z + rv[a].w * cv[bb].w;
    }
  }
  float* Out = z ? Pg : Ag;
#pragma unroll
  for (int a = 0; a < 4; ++a) {
    int t = ty * 4 + a;
    float4 o;
    float v0 = acc[a][0], v1 = acc[a][1], v2 = acc[a][2], v3 = acc[a][3];
    int i0 = tx * 4;
    if (z == 0) {
      o.x = (i0 + 0 < t) ? v0 : 0.0f; o.y = (i0 + 1 < t) ? v1 : 0.0f;
      o.z = (i0 + 2 < t) ? v2 : 0.0f; o.w = (i0 + 3 < t) ? v3 : 0.0f;
    } else {
      o.x = (i0 + 0 <= t) ? v0 : 0.0f; o.y = (i0 + 1 <= t) ? v1 : 0.0f;
      o.z = (i0 + 2 <= t) ? v2 : 0.0f; o.w = (i0 + 3 <= t) ? v3 : 0.0f;
    }
    *reinterpret_cast<float4*>(&Out[((cc * B_ + b) * CH + t) * 64 + i0]) = o;
  }
}

// ---------------------------------------------------------------------------
// KSp[ks][b][t][j] = sum_{d in split} K[t,d]*S[b][j][d]; same for QSp with Q.
// grid (16 jt, ksn, B_). Each split covers dlen d.
// ---------------------------------------------------------------------------
__global__ __launch_bounds__(256) void rhsqs_kernel(
    const float* __restrict__ Q, const float* __restrict__ K, const float* __restrict__ S,
    float* __restrict__ KSp, float* __restrict__ QSp, int cc, int tgs, int dlen)
{
  const int jt = blockIdx.x;
  const int ks = blockIdx.y;
  const int b = blockIdx.z;
  const int j0 = jt * 64;
  const int base = b * tgs + cc * CH;
  const int tid = threadIdx.x;
  const int tx = tid & 15, ty = tid >> 4;
  __shared__ float Ks_[64][68];
  __shared__ float Qs_[64][68];
  __shared__ float Ss[64][68];
  float accK[4][4] = {};
  float accQ[4][4] = {};
  const int dbeg = ks * dlen;
  for (int d0 = dbeg; d0 < dbeg + dlen; d0 += 64) {
    __syncthreads();
#pragma unroll
    for (int i = 0; i < 4; ++i) {
      int qq = tid + i * 256;
      int t = qq >> 4, dq = (qq & 15) * 4;
      int gidx = (base + t) * 1024 + d0 + dq;
      *reinterpret_cast<float4*>(&Ks_[t][dq]) = *reinterpret_cast<const float4*>(&K[gidx]);
      *reinterpret_cast<float4*>(&Qs_[t][dq]) = *reinterpret_cast<const float4*>(&Q[gidx]);
      *reinterpret_cast<float4*>(&Ss[t][dq]) =
          *reinterpret_cast<const float4*>(&S[b * 1048576 + (j0 + t) * 1024 + d0 + dq]);
    }
    __syncthreads();
#pragma unroll
    for (int dd = 0; dd < 64; dd += 4) {
      float4 sv[4], kv[4], qv[4];
#pragma unroll
      for (int bb = 0; bb < 4; ++bb) sv[bb] = *reinterpret_cast<const float4*>(&Ss[tx * 4 + bb][dd]);
#pragma unroll
      for (int a = 0; a < 4; ++a) {
        kv[a] = *reinterpret_cast<const float4*>(&Ks_[ty * 4 + a][dd]);
        qv[a] = *reinterpret_cast<const float4*>(&Qs_[ty * 4 + a][dd]);
      }
#pragma unroll
      for (int a = 0; a < 4; ++a)
#pragma unroll
        for (int bb = 0; bb < 4; ++bb) {
          accK[a][bb] += kv[a].x * sv[bb].x + kv[a].y * sv[bb].y +
                         kv[a].z * sv[bb].z + kv[a].w * sv[bb].w;
          accQ[a][bb] += qv[a].x * sv[bb].x + qv[a].y * sv[bb].y +
                         qv[a].z * sv[bb].z + qv[a].w * sv[bb].w;
        }
    }
  }
#pragma unroll
  for (int a = 0; a < 4; ++a) {
    int t = ty * 4 + a;
    int oidx = ((ks * B_ + b) * CH + t) * 1024 + j0 + tx * 4;
    *reinterpret_cast<float4*>(&KSp[oidx]) =
        make_float4(accK[a][0], accK[a][1], accK[a][2], accK[a][3]);
    *reinterpret_cast<float4*>(&QSp[oidx]) =
        make_float4(accQ[a][0], accQ[a][1], accQ[a][2], accQ[a][3]);
  }
}

// ---------------------------------------------------------------------------
// Triangular solve + chunk output, LDS-staged. grid (16 colgroups, B_),
// 256 threads: all stage RHS = V - sum KSp, QS = sum QSp, A, P into LDS;
// lanes 0..63 then solve one column each entirely out of LDS.
// ---------------------------------------------------------------------------
__global__ __launch_bounds__(256) void solve_kernel(
    const float* __restrict__ Ag, const float* __restrict__ Pg,
    const float* __restrict__ KSp, const float* __restrict__ QSp,
    const float* __restrict__ V, float* __restrict__ U, float* __restrict__ Og,
    int cc, int tgs, int ksn)
{
  const int cg = blockIdx.x;
  const int b = blockIdx.y;
  const int tid = threadIdx.x;
  const int col0 = cg * 64;
  const int base = b * tgs + cc * CH;
  __shared__ float RHS[64][68];   // V - sum KS   [t][col]
  __shared__ float QSl[64][68];   // sum QS       [t][col]
  __shared__ float Asm[64][64];
  __shared__ float Psm[64][64];
  const float* Ab = &Ag[((cc * B_ + b) * CH) * 64];
  const float* Pb = &Pg[((cc * B_ + b) * CH) * 64];
#pragma unroll
  for (int i = 0; i < 4; ++i) {
    int qq = tid + i * 256;
    int t = qq >> 4, c4 = (qq & 15) * 4;
    float4 r = *reinterpret_cast<const float4*>(&V[(base + t) * 1024 + col0 + c4]);
    float4 qs = make_float4(0.f, 0.f, 0.f, 0.f);
    for (int ks = 0; ks < ksn; ++ks) {
      int pidx = ((ks * B_ + b) * CH + t) * 1024 + col0 + c4;
      float4 kp = *reinterpret_cast<const float4*>(&KSp[pidx]);
      float4 qp = *reinterpret_cast<const float4*>(&QSp[pidx]);
      r.x -= kp.x; r.y -= kp.y; r.z -= kp.z; r.w -= kp.w;
      qs.x += qp.x; qs.y += qp.y; qs.z += qp.z; qs.w += qp.w;
    }
    *reinterpret_cast<float4*>(&RHS[t][c4]) = r;
    *reinterpret_cast<float4*>(&QSl[t][c4]) = qs;
    // A/P staging: 4096 floats each over 1024 thread-slots
    int t2 = qq >> 4, i4 = (qq & 15) * 4;
    *reinterpret_cast<float4*>(&Asm[t2][i4]) = *reinterpret_cast<const float4*>(&Ab[t2 * 64 + i4]);
    *reinterpret_cast<float4*>(&Psm[t2][i4]) = *reinterpret_cast<const float4*>(&Pb[t2 * 64 + i4]);
  }
  __syncthreads();

  if (tid < 64) {
    const int col = col0 + tid;
    float u[64];
#pragma unroll
    for (int t = 0; t < 64; ++t) {
      float x = RHS[t][tid];
      float s0 = 0.f, s1 = 0.f, s2 = 0.f, s3 = 0.f;
      for (int i0 = 0; i0 + 4 <= t; i0 += 4) {
        float4 a4 = *reinterpret_cast<const float4*>(&Asm[t][i0]);
        s0 += a4.x * u[i0 + 0]; s1 += a4.y * u[i0 + 1];
        s2 += a4.z * u[i0 + 2]; s3 += a4.w * u[i0 + 3];
      }
      for (int i = (t >> 2) << 2; i < t; ++i) s0 += Asm[t][i] * u[i];
      u[t] = x - ((s0 + s1) + (s2 + s3));
    }
#pragma unroll
    for (int t = 0; t < 64; ++t) {
      float o = QSl[t][tid];
      float s0 = 0.f, s1 = 0.f, s2 = 0.f, s3 = 0.f;
      for (int i0 = 0; i0 + 4 <= t + 1; i0 += 4) {
        float4 p4 = *reinterpret_cast<const float4*>(&Psm[t][i0]);
        s0 += p4.x * u[i0 + 0]; s1 += p4.y * u[i0 + 1];
        s2 += p4.z * u[i0 + 2]; s3 += p4.w * u[i0 + 3];
      }
      for (int i = ((t + 1) >> 2) << 2; i <= t; ++i) s0 += Psm[t][i] * u[i];
      o += (s0 + s1) + (s2 + s3);
      U[(b * CH + t) * 1024 + col] = u[t];
      Og[(base + t) * 1024 + col] = o;
    }
  }
}

// ---------------------------------------------------------------------------
// S[b][j][d] += sum_t U[t][j] * K[t][d]   (rank-64 update), grid (16,16,B_)
// ---------------------------------------------------------------------------
__global__ __launch_bounds__(256) void supdate_kernel(
    const float* __restrict__ U, const float* __restrict__ K, float* __restrict__ S,
    int cc, int tgs)
{
  const int d0 = blockIdx.x * 64;
  const int j0 = blockIdx.y * 64;
  const int b = blockIdx.z;
  const int base = b * tgs + cc * CH;
  const int tid = threadIdx.x;
  const int tx = tid & 15, ty = tid >> 4;
  __shared__ float Us[64][68];
  __shared__ float Ks[64][68];
#pragma unroll
  for (int i = 0; i < 4; ++i) {
    int qq = tid + i * 256;
    int t = qq >> 4, xq = (qq & 15) * 4;
    *reinterpret_cast<float4*>(&Us[t][xq]) =
        *reinterpret_cast<const float4*>(&U[(b * CH + t) * 1024 + j0 + xq]);
    *reinterpret_cast<float4*>(&Ks[t][xq]) =
        *reinterpret_cast<const float4*>(&K[(base + t) * 1024 + d0 + xq]);
  }
  __syncthreads();
  float acc[4][4] = {};
#pragma unroll
  for (int t = 0; t < 64; ++t) {
    float4 u4 = *reinterpret_cast<const float4*>(&Us[t][ty * 4]);
    float4 k4 = *reinterpret_cast<const float4*>(&Ks[t][tx * 4]);
    float ua[4] = {u4.x, u4.y, u4.z, u4.w};
    float kb[4] = {k4.x, k4.y, k4.z, k4.w};
#pragma unroll
    for (int a = 0; a < 4; ++a)
#pragma unroll
      for (int bb = 0; bb < 4; ++bb) acc[a][bb] += ua[a] * kb[bb];
  }
#pragma unroll
  for (int a = 0; a < 4; ++a) {
    int idx = b * 1048576 + (j0 + ty * 4 + a) * 1024 + d0 + tx * 4;
    float4 s4 = *reinterpret_cast<float4*>(&S[idx]);
    s4.x += acc[a][0]; s4.y += acc[a][1]; s4.z += acc[a][2]; s4.w += acc[a][3];
    *reinterpret_cast<float4*>(&S[idx]) = s4;
  }
}

// ---------------------------------------------------------------------------
extern "C" void kernel_launch(void* const* d_in, const int* in_sizes, int n_in,
                              void* d_out, int out_size, void* d_ws, size_t ws_size,
                              hipStream_t stream) {
  const float* x  = (const float*)d_in[0];
  const float* Wq = (const float*)d_in[1];
  const float* Wk = (const float*)d_in[2];
  const float* Wv = (const float*)d_in[3];
  const float* Wo = (const float*)d_in[4];
  float* out = (float*)d_out;

  // --- tier selection: largest time-group that fits ws_size ---
  // buffers: Q/K/V/O: B_*tgs*1024*4 each; S 16MB; A/P: cpg*B_*64*64*4 each;
  // KSp/QSp: ksn*B_*64*1024*4 each; U 1MB.  (+slop for 256B alignment)
  int lsh = 8, ksn = 2;
  {
    const int cand_lsh[4] = {11, 10, 9, 8};
    const int cand_ksn[4] = {4, 4, 4, 2};
    for (int i = 0; i < 4; ++i) {
      size_t tgs = (size_t)1 << cand_lsh[i];
      size_t cpg = tgs / CH;
      size_t need = 4 * (B_ * tgs * 1024 * 4)            // Q,K,V,O
                  + (size_t)B_ * 1024 * 1024 * 4          // S
                  + 2 * (cpg * B_ * CH * 64 * 4)          // A,P
                  + 2 * ((size_t)cand_ksn[i] * B_ * CH * 1024 * 4) // KSp,QSp
                  + (size_t)B_ * CH * 1024 * 4            // U
                  + 16384;                                // align slop
      if (need <= ws_size) { lsh = cand_lsh[i]; ksn = cand_ksn[i]; break; }
    }
  }
  const int tgs = 1 << lsh;
  const int cpg = tgs / CH;
  const int ngrp = T_ / tgs;
  const int dlen = 1024 / ksn;
  const int rows = B_ * tgs;

  char* ws = (char*)d_ws;
  size_t off = 0;
  auto alloc = [&](size_t bytes) -> void* {
    void* p = ws + off;
    off += (bytes + 255) & ~(size_t)255;
    return p;
  };
  float* Qg = (float*)alloc((size_t)rows * 1024 * 4);
  float* Kg = (float*)alloc((size_t)rows * 1024 * 4);
  float* Vg = (float*)alloc((size_t)rows * 1024 * 4);
  float* Og = (float*)alloc((size_t)rows * 1024 * 4);
  float* S   = (float*)alloc((size_t)B_ * 1024 * 1024 * 4);
  float* Ag  = (float*)alloc((size_t)cpg * B_ * CH * 64 * 4);
  float* Pg  = (float*)alloc((size_t)cpg * B_ * CH * 64 * 4);
  float* KSp = (float*)alloc((size_t)ksn * B_ * CH * 1024 * 4);
  float* QSp = (float*)alloc((size_t)ksn * B_ * CH * 1024 * 4);
  float* U   = (float*)alloc((size_t)B_ * CH * 1024 * 4);

  hipMemsetAsync(S, 0, (size_t)B_ * 1024 * 1024 * 4, stream);

  for (int g = 0; g < ngrp; ++g) {
    int tg = g * tgs;
    gemm_qkv<<<dim3(rows / 128, 8, 3), 256, 0, stream>>>(x, Wq, Wk, Wv, Qg, Kg, Vg, tg, lsh);
    knorm_kernel<<<rows, 256, 0, stream>>>(Kg);
    attn_all_kernel<<<dim3(2, B_, cpg), 256, 0, stream>>>(Qg, Kg, Ag, Pg, tgs);
    for (int cc = 0; cc < cpg; ++cc) {
      rhsqs_kernel<<<dim3(16, ksn, B_), 256, 0, stream>>>(Qg, Kg, S, KSp, QSp, cc, tgs, dlen);
      solve_kernel<<<dim3(16, B_), 256, 0, stream>>>(Ag, Pg, KSp, QSp, Vg, U, Og, cc, tgs, ksn);
      supdate_kernel<<<dim3(16, 16, B_), 256, 0, stream>>>(U, Kg, S, cc, tgs);
    }
    gemm_out<<<dim3(rows / 64, 16), 256, 0, stream>>>(Og, Wo, out, tg, lsh);
  }
}